// Round 1
// baseline (275.573 us; speedup 1.0000x reference)
//
#include <hip/hip_runtime.h>
#include <math.h>

// Problem constants (match reference)
constexpr int Bn = 4, Cn = 12, Hn = 256, Wn = 256;
constexpr int HWn  = Hn * Wn;        // 65536
constexpr int NPIX = Bn * HWn;       // 262144
constexpr int NMASK = 2 * Bn * Cn;   // 96 masks (48 pred + 48 target)
constexpr int NJOB  = 2 * NMASK;     // 192 EDT jobs (edt(mask), edt(~mask))
constexpr float LARGEf  = 1.0e6f;
constexpr float LARGE2f = 1.0e12f;

// ---------------------------------------------------------------------------
// Kernel A: per-pixel softmax -> pred masks (prob>0.5) and target one-hot masks
// ---------------------------------------------------------------------------
__global__ void masks_kernel(const float* __restrict__ pred,
                             const int* __restrict__ target,
                             unsigned char* __restrict__ masks) {
    int pix = blockIdx.x * blockDim.x + threadIdx.x;   // grid sized exactly NPIX
    int b = pix >> 16;            // / HW
    int p = pix & (HWn - 1);
    float v[Cn];
    float mx = -3.4e38f;
#pragma unroll
    for (int c = 0; c < Cn; ++c) {
        v[c] = pred[(size_t)(b * Cn + c) * HWn + p];
        mx = fmaxf(mx, v[c]);
    }
    float s = 0.f;
#pragma unroll
    for (int c = 0; c < Cn; ++c) { v[c] = expf(v[c] - mx); s += v[c]; }
    int t = target[pix];
#pragma unroll
    for (int c = 0; c < Cn; ++c) {
        float prob = v[c] / s;
        masks[(size_t)(b * Cn + c) * HWn + p] = (prob > 0.5f) ? 1 : 0;                 // pred mask id = b*C+c
        masks[(size_t)(Bn * Cn + b * Cn + c) * HWn + p] = (c == t) ? 1 : 0;            // target mask id = 48 + b*C+c
    }
}

// ---------------------------------------------------------------------------
// Kernel B: has_fg per mask (any true pixel)
// ---------------------------------------------------------------------------
__global__ void hasfg_kernel(const unsigned char* __restrict__ masks,
                             int* __restrict__ has_fg) {
    int m = blockIdx.x, tid = threadIdx.x;
    const uint4* mp = (const uint4*)(masks + (size_t)m * HWn);
    unsigned acc = 0;
    for (int i = tid; i < HWn / 16; i += 256) {
        uint4 u = mp[i];
        acc |= u.x | u.y | u.z | u.w;
    }
    __shared__ unsigned sh[256];
    sh[tid] = acc;
    __syncthreads();
    for (int s = 128; s > 0; s >>= 1) {
        if (tid < s) sh[tid] |= sh[tid + s];
        __syncthreads();
    }
    if (tid == 0) has_fg[m] = sh[0] ? 1 : 0;
}

// ---------------------------------------------------------------------------
// Kernel C: column pass. job jb: feature = !mask (jb<96, edt(mask)) or mask
// (jb>=96, edt(~mask)). Forward+backward saturating scan along H, write g^2.
// One thread per (job, column).
// ---------------------------------------------------------------------------
__global__ void colpass_kernel(const unsigned char* __restrict__ masks,
                               float* __restrict__ g2) {
    int jb = blockIdx.x;          // 0..191
    int j  = threadIdx.x;         // 0..255 column
    int m  = (jb < NMASK) ? jb : jb - NMASK;
    int invert = (jb < NMASK);    // feature = !mask for edt(mask)
    const unsigned char* mp = masks + (size_t)m * HWn;
    float* gp = g2 + (size_t)jb * HWn;
    unsigned bits[8] = {0, 0, 0, 0, 0, 0, 0, 0};   // feature column bit-packed
    float c = LARGEf;
    for (int i = 0; i < Hn; ++i) {
        int v = mp[i * Wn + j];
        int feat = invert ? (v == 0) : (v != 0);
        bits[i >> 5] |= (unsigned)feat << (i & 31);
        c = feat ? 0.f : fminf(c + 1.f, LARGEf);
        gp[i * Wn + j] = c;                         // store forward distance
    }
    c = LARGEf;
    for (int i = Hn - 1; i >= 0; --i) {
        int feat = (bits[i >> 5] >> (i & 31)) & 1;
        c = feat ? 0.f : fminf(c + 1.f, LARGEf);
        float g = fminf(c, gp[i * Wn + j]);         // min(fwd, bwd)
        gp[i * Wn + j] = g * g;
    }
}

// ---------------------------------------------------------------------------
// Kernel D: row pass, both polarities fused. Block = (mask m, row i).
// D2[j] = min_j' g2[j'] + (j-j')^2 (exact, matches reference scan arithmetic).
// field = sqrt(D2_pos) + sqrt(D2_neg) written IN PLACE over g2 plane m
// (safe: this block is the only consumer of those two rows).
// ---------------------------------------------------------------------------
__global__ void rowpass_kernel(float* __restrict__ g2) {
    int blk = blockIdx.x;             // 0 .. NMASK*H-1
    int m = blk >> 8;                 // / Hn
    int i = blk & (Hn - 1);
    int j = threadIdx.x;
    __shared__ float rA[Wn], rB[Wn];
    float* rowp = g2 + (size_t)m * HWn + i * Wn;              // edt(mask) g2
    const float* rowq = g2 + (size_t)(m + NMASK) * HWn + i * Wn;  // edt(~mask) g2
    rA[j] = rowp[j];
    rB[j] = rowq[j];
    __syncthreads();
    float m0 = LARGE2f, m1 = LARGE2f;
#pragma unroll 8
    for (int jp = 0; jp < Wn; ++jp) {
        int d = j - jp;
        float off = (float)(d * d);
        m0 = fminf(m0, rA[jp] + off);
        m1 = fminf(m1, rB[jp] + off);
    }
    rowp[j] = sqrtf(m0) + sqrtf(m1);   // field = edt(mask) + edt(~mask)
}

// ---------------------------------------------------------------------------
// Kernel E: loss accumulation (deterministic block partials, double precision)
// ---------------------------------------------------------------------------
__global__ void loss_kernel(const float* __restrict__ pred,
                            const int* __restrict__ target,
                            const float* __restrict__ field,   // g2 planes 0..95
                            const int* __restrict__ has_fg,
                            double* __restrict__ partials) {
    int pix = blockIdx.x * blockDim.x + threadIdx.x;
    int b = pix >> 16;
    int p = pix & (HWn - 1);
    float v[Cn];
    float mx = -3.4e38f;
#pragma unroll
    for (int c = 0; c < Cn; ++c) {
        v[c] = pred[(size_t)(b * Cn + c) * HWn + p];
        mx = fmaxf(mx, v[c]);
    }
    int t = target[pix];
    float raw_t = 0.f;
    float s = 0.f;
#pragma unroll
    for (int c = 0; c < Cn; ++c) {
        if (c == t) raw_t = v[c];
        v[c] = expf(v[c] - mx);
        s += v[c];
    }
    float logp_t = raw_t - mx - logf(s);
    double acc = 0.0;
#pragma unroll
    for (int c = 0; c < Cn; ++c) {
        float prob = v[c] / s;
        float oh = (c == t) ? 1.0f : 0.0f;
        float err = (prob - oh) * (prob - oh);
        int mpid = b * Cn + c;
        int mtid = Bn * Cn + b * Cn + c;
        float fp = has_fg[mpid] ? field[(size_t)mpid * HWn + p] : 0.0f;
        float ft = has_fg[mtid] ? field[(size_t)mtid * HWn + p] : 0.0f;
        float dist = fp * fp + ft * ft;   // ALPHA = 2
        acc += (double)(err * dist);
    }
    __shared__ double shl[256];
    __shared__ double shc[256];
    shl[threadIdx.x] = acc;
    shc[threadIdx.x] = (double)logp_t;
    __syncthreads();
    for (int s2 = 128; s2 > 0; s2 >>= 1) {
        if (threadIdx.x < s2) {
            shl[threadIdx.x] += shl[threadIdx.x + s2];
            shc[threadIdx.x] += shc[threadIdx.x + s2];
        }
        __syncthreads();
    }
    if (threadIdx.x == 0) {
        partials[blockIdx.x] = shl[0];
        partials[1024 + blockIdx.x] = shc[0];
    }
}

// ---------------------------------------------------------------------------
// Kernel F: final reduction -> scalar
// ---------------------------------------------------------------------------
__global__ void final_kernel(const double* __restrict__ partials,
                             float* __restrict__ out) {
    int tid = threadIdx.x;
    double a = 0.0, ce = 0.0;
    for (int i = tid; i < 1024; i += 256) {
        a  += partials[i];
        ce += partials[1024 + i];
    }
    __shared__ double sa[256], sc[256];
    sa[tid] = a; sc[tid] = ce;
    __syncthreads();
    for (int s = 128; s > 0; s >>= 1) {
        if (tid < s) { sa[tid] += sa[tid + s]; sc[tid] += sc[tid + s]; }
        __syncthreads();
    }
    if (tid == 0) {
        double loss_sum = sa[0] / (double)NPIX;        // sum_c mean_{b,h,w}
        double cem = -sc[0] / (double)NPIX;            // ce
        double res = loss_sum / (double)Cn / (double)Bn / 3.0 + cem;
        out[0] = (float)res;
    }
}

// ---------------------------------------------------------------------------
extern "C" void kernel_launch(void* const* d_in, const int* in_sizes, int n_in,
                              void* d_out, int out_size, void* d_ws, size_t ws_size,
                              hipStream_t stream) {
    const float* pred  = (const float*)d_in[0];
    const int* target  = (const int*)d_in[1];
    float* out = (float*)d_out;
    char* ws = (char*)d_ws;

    // workspace layout (~54 MB total)
    unsigned char* masks = (unsigned char*)ws;                       // 96*65536 = 6,291,456 B
    size_t off = (size_t)NMASK * HWn;
    float* g2 = (float*)(ws + off);                                  // 192*65536*4 = 50,331,648 B
    off += (size_t)NJOB * HWn * 4;
    int* has_fg = (int*)(ws + off);                                  // 96*4 B (padded to 512)
    off += 512;
    double* partials = (double*)(ws + off);                          // 2048*8 B

    masks_kernel<<<NPIX / 256, 256, 0, stream>>>(pred, target, masks);
    hasfg_kernel<<<NMASK, 256, 0, stream>>>(masks, has_fg);
    colpass_kernel<<<NJOB, 256, 0, stream>>>(masks, g2);
    rowpass_kernel<<<NMASK * Hn, 256, 0, stream>>>(g2);
    loss_kernel<<<NPIX / 256, 256, 0, stream>>>(pred, target, g2, has_fg, partials);
    final_kernel<<<1, 256, 0, stream>>>(partials, out);
}

// Round 2
// 146.374 us; speedup vs baseline: 1.8827x; 1.8827x over previous
//
#include <hip/hip_runtime.h>
#include <math.h>

// Problem constants (match reference)
constexpr int Bn = 4, Cn = 12, Hn = 256, Wn = 256;
constexpr int HWn  = Hn * Wn;        // 65536
constexpr int NPIX = Bn * HWn;       // 262144
constexpr int NMASK = 2 * Bn * Cn;   // 96 masks (48 pred + 48 target)
constexpr int NJOB  = 2 * NMASK;     // 192 EDT jobs (edt(mask), edt(~mask))
constexpr float LARGEf  = 1.0e6f;

// ---------------------------------------------------------------------------
// Kernel A: per-pixel softmax -> pred masks (prob>0.5) and target one-hot masks
// ---------------------------------------------------------------------------
__global__ void masks_kernel(const float* __restrict__ pred,
                             const int* __restrict__ target,
                             unsigned char* __restrict__ masks) {
    int pix = blockIdx.x * blockDim.x + threadIdx.x;   // grid sized exactly NPIX
    int b = pix >> 16;            // / HW
    int p = pix & (HWn - 1);
    float v[Cn];
    float mx = -3.4e38f;
#pragma unroll
    for (int c = 0; c < Cn; ++c) {
        v[c] = pred[(size_t)(b * Cn + c) * HWn + p];
        mx = fmaxf(mx, v[c]);
    }
    float s = 0.f;
#pragma unroll
    for (int c = 0; c < Cn; ++c) { v[c] = expf(v[c] - mx); s += v[c]; }
    int t = target[pix];
#pragma unroll
    for (int c = 0; c < Cn; ++c) {
        float prob = v[c] / s;
        masks[(size_t)(b * Cn + c) * HWn + p] = (prob > 0.5f) ? 1 : 0;                 // pred mask id = b*C+c
        masks[(size_t)(Bn * Cn + b * Cn + c) * HWn + p] = (c == t) ? 1 : 0;            // target mask id = 48 + b*C+c
    }
}

// ---------------------------------------------------------------------------
// Kernel B: per-mask flags: bit0 = has_true (any fg), bit1 = has_false
// ---------------------------------------------------------------------------
__global__ void flags_kernel(const unsigned char* __restrict__ masks,
                             int* __restrict__ flags) {
    int m = blockIdx.x, tid = threadIdx.x;
    const uint4* mp = (const uint4*)(masks + (size_t)m * HWn);
    unsigned acc_or = 0, acc_and = 0xFFFFFFFFu;
    for (int i = tid; i < HWn / 16; i += 256) {
        uint4 u = mp[i];
        acc_or  |= u.x | u.y | u.z | u.w;
        acc_and &= u.x & u.y & u.z & u.w;
    }
    __shared__ unsigned sor[256], sand[256];
    sor[tid] = acc_or; sand[tid] = acc_and;
    __syncthreads();
    for (int s = 128; s > 0; s >>= 1) {
        if (tid < s) { sor[tid] |= sor[tid + s]; sand[tid] &= sand[tid + s]; }
        __syncthreads();
    }
    if (tid == 0) {
        int has_true  = sor[0] ? 1 : 0;
        int has_false = (sand[0] != 0x01010101u) ? 2 : 0;   // bytes are 0 or 1
        flags[m] = has_true | has_false;
    }
}

// ---------------------------------------------------------------------------
// Kernel C: column pass. job jb: feature = !mask (jb<96, edt(mask)) or mask
// (jb>=96, edt(~mask)). Forward+backward saturating scan along H, write g^2.
// One thread per (job, column). Skips planes whose field is never consumed.
// ---------------------------------------------------------------------------
__global__ void colpass_kernel(const unsigned char* __restrict__ masks,
                               const int* __restrict__ flags,
                               float* __restrict__ g2) {
    int jb = blockIdx.x;          // 0..191
    int j  = threadIdx.x;         // 0..255 column
    int m  = (jb < NMASK) ? jb : jb - NMASK;
    if (!(flags[m] & 1)) return;  // has_fg==0 -> field plane m unused by loss
    int invert = (jb < NMASK);    // feature = !mask for edt(mask)
    const unsigned char* mp = masks + (size_t)m * HWn;
    float* gp = g2 + (size_t)jb * HWn;
    unsigned bits[8] = {0, 0, 0, 0, 0, 0, 0, 0};   // feature column bit-packed
    float c = LARGEf;
    for (int i = 0; i < Hn; ++i) {
        int v = mp[i * Wn + j];
        int feat = invert ? (v == 0) : (v != 0);
        bits[i >> 5] |= (unsigned)feat << (i & 31);
        c = feat ? 0.f : fminf(c + 1.f, LARGEf);
        gp[i * Wn + j] = c;                         // store forward distance
    }
    c = LARGEf;
    for (int i = Hn - 1; i >= 0; --i) {
        int feat = (bits[i >> 5] >> (i & 31)) & 1;
        c = feat ? 0.f : fminf(c + 1.f, LARGEf);
        float g = fminf(c, gp[i * Wn + j]);         // min(fwd, bwd)
        gp[i * Wn + j] = g * g;
    }
}

// ---------------------------------------------------------------------------
// Kernel D: row pass, both polarities fused, OUTWARD scan with early exit.
// d2[j] = min_k g2[j+-k] + k^2; once k^2 >= running min, all remaining
// candidates are >= k^2 >= min, so stop. Exact: all finite candidates are
// exact integers in fp32 (min is order-independent); saturated 1e12 case
// rounds identically to the reference chain.
// field = sqrt(d2_pos) + sqrt(d2_neg) written IN PLACE over g2 plane m.
// ---------------------------------------------------------------------------
__global__ void rowpass_kernel(float* __restrict__ g2,
                               const int* __restrict__ flags) {
    int blk = blockIdx.x;             // 0 .. NMASK*H-1
    int m = blk >> 8;                 // / Hn
    int i = blk & (Hn - 1);
    int j = threadIdx.x;
    if (!(flags[m] & 1)) return;      // field plane unused
    __shared__ float2 rAB[Wn];
    float* rowp = g2 + (size_t)m * HWn + i * Wn;                  // edt(mask) g2
    const float* rowq = g2 + (size_t)(m + NMASK) * HWn + i * Wn;  // edt(~mask) g2
    float a = rowp[j];
    float b = rowq[j];
    rAB[j] = make_float2(a, b);
    __syncthreads();
    float m0 = a, m1 = b;             // candidate k=0
    for (int k = 1; k < Wn; ++k) {
        float k2 = (float)(k * k);
        if (k2 >= m0 && k2 >= m1) break;
        int jl = j - k, jr = j + k;
        if (jl < 0 && jr >= Wn) break;
        if (jl >= 0) {
            float2 v = rAB[jl];
            m0 = fminf(m0, k2 + v.x);
            m1 = fminf(m1, k2 + v.y);
        }
        if (jr < Wn) {
            float2 v = rAB[jr];
            m0 = fminf(m0, k2 + v.x);
            m1 = fminf(m1, k2 + v.y);
        }
    }
    rowp[j] = sqrtf(m0) + sqrtf(m1);   // field = edt(mask) + edt(~mask)
}

// ---------------------------------------------------------------------------
// Kernel E: loss accumulation (deterministic block partials, double precision)
// ---------------------------------------------------------------------------
__global__ void loss_kernel(const float* __restrict__ pred,
                            const int* __restrict__ target,
                            const float* __restrict__ field,   // g2 planes 0..95
                            const int* __restrict__ flags,
                            double* __restrict__ partials) {
    int pix = blockIdx.x * blockDim.x + threadIdx.x;
    int b = pix >> 16;
    int p = pix & (HWn - 1);
    float v[Cn];
    float mx = -3.4e38f;
#pragma unroll
    for (int c = 0; c < Cn; ++c) {
        v[c] = pred[(size_t)(b * Cn + c) * HWn + p];
        mx = fmaxf(mx, v[c]);
    }
    int t = target[pix];
    float raw_t = 0.f;
    float s = 0.f;
#pragma unroll
    for (int c = 0; c < Cn; ++c) {
        if (c == t) raw_t = v[c];
        v[c] = expf(v[c] - mx);
        s += v[c];
    }
    float logp_t = raw_t - mx - logf(s);
    double acc = 0.0;
#pragma unroll
    for (int c = 0; c < Cn; ++c) {
        float prob = v[c] / s;
        float oh = (c == t) ? 1.0f : 0.0f;
        float err = (prob - oh) * (prob - oh);
        int mpid = b * Cn + c;
        int mtid = Bn * Cn + b * Cn + c;
        float fp = (flags[mpid] & 1) ? field[(size_t)mpid * HWn + p] : 0.0f;
        float ft = (flags[mtid] & 1) ? field[(size_t)mtid * HWn + p] : 0.0f;
        float dist = fp * fp + ft * ft;   // ALPHA = 2
        acc += (double)(err * dist);
    }
    __shared__ double shl[256];
    __shared__ double shc[256];
    shl[threadIdx.x] = acc;
    shc[threadIdx.x] = (double)logp_t;
    __syncthreads();
    for (int s2 = 128; s2 > 0; s2 >>= 1) {
        if (threadIdx.x < s2) {
            shl[threadIdx.x] += shl[threadIdx.x + s2];
            shc[threadIdx.x] += shc[threadIdx.x + s2];
        }
        __syncthreads();
    }
    if (threadIdx.x == 0) {
        partials[blockIdx.x] = shl[0];
        partials[1024 + blockIdx.x] = shc[0];
    }
}

// ---------------------------------------------------------------------------
// Kernel F: final reduction -> scalar
// ---------------------------------------------------------------------------
__global__ void final_kernel(const double* __restrict__ partials,
                             float* __restrict__ out) {
    int tid = threadIdx.x;
    double a = 0.0, ce = 0.0;
    for (int i = tid; i < 1024; i += 256) {
        a  += partials[i];
        ce += partials[1024 + i];
    }
    __shared__ double sa[256], sc[256];
    sa[tid] = a; sc[tid] = ce;
    __syncthreads();
    for (int s = 128; s > 0; s >>= 1) {
        if (tid < s) { sa[tid] += sa[tid + s]; sc[tid] += sc[tid + s]; }
        __syncthreads();
    }
    if (tid == 0) {
        double loss_sum = sa[0] / (double)NPIX;        // sum_c mean_{b,h,w}
        double cem = -sc[0] / (double)NPIX;            // ce
        double res = loss_sum / (double)Cn / (double)Bn / 3.0 + cem;
        out[0] = (float)res;
    }
}

// ---------------------------------------------------------------------------
extern "C" void kernel_launch(void* const* d_in, const int* in_sizes, int n_in,
                              void* d_out, int out_size, void* d_ws, size_t ws_size,
                              hipStream_t stream) {
    const float* pred  = (const float*)d_in[0];
    const int* target  = (const int*)d_in[1];
    float* out = (float*)d_out;
    char* ws = (char*)d_ws;

    // workspace layout (~54 MB total)
    unsigned char* masks = (unsigned char*)ws;                       // 96*65536 = 6,291,456 B
    size_t off = (size_t)NMASK * HWn;
    float* g2 = (float*)(ws + off);                                  // 192*65536*4 = 50,331,648 B
    off += (size_t)NJOB * HWn * 4;
    int* flags = (int*)(ws + off);                                   // 96*4 B (padded to 512)
    off += 512;
    double* partials = (double*)(ws + off);                          // 2048*8 B

    masks_kernel<<<NPIX / 256, 256, 0, stream>>>(pred, target, masks);
    flags_kernel<<<NMASK, 256, 0, stream>>>(masks, flags);
    colpass_kernel<<<NJOB, 256, 0, stream>>>(masks, flags, g2);
    rowpass_kernel<<<NMASK * Hn, 256, 0, stream>>>(g2, flags);
    loss_kernel<<<NPIX / 256, 256, 0, stream>>>(pred, target, g2, flags, partials);
    final_kernel<<<1, 256, 0, stream>>>(partials, out);
}

// Round 3
// 140.204 us; speedup vs baseline: 1.9655x; 1.0440x over previous
//
#include <hip/hip_runtime.h>
#include <math.h>

// Problem constants (match reference)
constexpr int Bn = 4, Cn = 12, Hn = 256, Wn = 256;
constexpr int HWn  = Hn * Wn;        // 65536
constexpr int NPIX = Bn * HWn;       // 262144
constexpr int NMASK = 2 * Bn * Cn;   // 96 masks (48 pred + 48 target)
constexpr int NJOB  = 2 * NMASK;     // 192 EDT jobs (edt(mask), edt(~mask))
constexpr float LARGEf  = 1.0e6f;

// fgflags layout: [0..3] = predfg bitmask per batch (bit c), [4..7] = tgtfg

// ---------------------------------------------------------------------------
// Kernel Z: zero the fg flag words
// ---------------------------------------------------------------------------
__global__ void zero_kernel(unsigned int* __restrict__ fgflags) {
    if (threadIdx.x < 8) fgflags[threadIdx.x] = 0u;
}

// ---------------------------------------------------------------------------
// Kernel A: per-pixel softmax -> pred masks (prob>0.5) and target one-hot
// masks; also accumulates per-mask has_fg bits via block OR + atomicOr.
// ---------------------------------------------------------------------------
__global__ void masks_kernel(const float* __restrict__ pred,
                             const int* __restrict__ target,
                             unsigned char* __restrict__ masks,
                             unsigned int* __restrict__ fgflags) {
    int pix = blockIdx.x * blockDim.x + threadIdx.x;   // grid sized exactly NPIX
    int b = pix >> 16;            // / HW  (each block lies within one b)
    int p = pix & (HWn - 1);
    float v[Cn];
    float mx = -3.4e38f;
#pragma unroll
    for (int c = 0; c < Cn; ++c) {
        v[c] = pred[(size_t)(b * Cn + c) * HWn + p];
        mx = fmaxf(mx, v[c]);
    }
    float s = 0.f;
#pragma unroll
    for (int c = 0; c < Cn; ++c) { v[c] = expf(v[c] - mx); s += v[c]; }
    int t = target[pix];
    unsigned word = 1u << (Cn + t);   // target one-hot fg bit
#pragma unroll
    for (int c = 0; c < Cn; ++c) {
        float prob = v[c] / s;
        int pb = (prob > 0.5f) ? 1 : 0;
        word |= (unsigned)pb << c;
        masks[(size_t)(b * Cn + c) * HWn + p] = (unsigned char)pb;           // pred mask
        masks[(size_t)(Bn * Cn + b * Cn + c) * HWn + p] = (c == t) ? 1 : 0;  // target mask
    }
    __shared__ unsigned sh[256];
    sh[threadIdx.x] = word;
    __syncthreads();
    for (int s2 = 128; s2 > 0; s2 >>= 1) {
        if (threadIdx.x < s2) sh[threadIdx.x] |= sh[threadIdx.x + s2];
        __syncthreads();
    }
    if (threadIdx.x == 0) {
        unsigned w = sh[0];
        atomicOr(&fgflags[b], w & 0xFFFu);
        atomicOr(&fgflags[4 + b], w >> Cn);
    }
}

__device__ __forceinline__ int mask_has_fg(const unsigned int* fgflags, int m) {
    int mm = (m < Bn * Cn) ? m : m - Bn * Cn;
    int b = mm / Cn, c = mm % Cn;
    unsigned fg = (m < Bn * Cn) ? fgflags[b] : fgflags[4 + b];
    return (fg >> c) & 1;
}

// ---------------------------------------------------------------------------
// Kernel C: segmented column pass. Block = (job jb, column-group of 64).
// 4 segments of 64 rows per column, one thread per (segment, column).
// Local fwd/bwd scans -> LDS (u8, 255 = LARGE sentinel); combine via segment
// end-states: inflow in[s] = min(e[s-1], min(in[s-1]+64, LARGE));
// true[i] = min(loc[i], min(inflow + steps, LARGE)). Exact integer fp32.
// ---------------------------------------------------------------------------
constexpr int SEG  = 4;
constexpr int SEGR = Hn / SEG;   // 64
constexpr int STRb = 68;         // LDS byte stride per thread (17 words, coprime banks)

__global__ void colpass_kernel(const unsigned char* __restrict__ masks,
                               const unsigned int* __restrict__ fgflags,
                               float* __restrict__ g2) {
    int blk = blockIdx.x;         // 0..767
    int jb = blk >> 2;            // job 0..191
    int cg = blk & 3;             // column group
    int m  = (jb < NMASK) ? jb : jb - NMASK;
    if (!mask_has_fg(fgflags, m)) return;   // field plane never consumed
    int invert = (jb < NMASK);    // feature = !mask for edt(mask)
    int tid = threadIdx.x;
    int s  = tid >> 6;            // segment 0..3 (uniform per wave)
    int jl = tid & 63;
    int j  = cg * 64 + jl;
    int r0 = s * SEGR;
    const unsigned char* mp = masks + (size_t)m * HWn;
    float* gp = g2 + (size_t)jb * HWn;

    __shared__ unsigned char ldsF[256 * STRb];
    __shared__ unsigned char ldsB[256 * STRb];
    __shared__ float eF[256], eB[256];

    unsigned b0 = 0, b1 = 0;
    float c = LARGEf;
    for (int i = 0; i < SEGR; ++i) {
        int v = mp[(r0 + i) * Wn + j];
        int feat = invert ? (v == 0) : (v != 0);
        if (i < 32) b0 |= (unsigned)feat << i; else b1 |= (unsigned)feat << (i - 32);
        c = feat ? 0.f : fminf(c + 1.f, LARGEf);
        ldsF[tid * STRb + i] = (unsigned char)fminf(c, 255.f);   // <=63 or sentinel 255
    }
    eF[tid] = c;
    c = LARGEf;
    for (int i = SEGR - 1; i >= 0; --i) {
        int feat = (int)(((i < 32) ? (b0 >> i) : (b1 >> (i - 32))) & 1u);
        c = feat ? 0.f : fminf(c + 1.f, LARGEf);
        ldsB[tid * STRb + i] = (unsigned char)fminf(c, 255.f);
    }
    eB[tid] = c;
    __syncthreads();
    float x = LARGEf;                         // fwd inflow to my segment
    for (int sp = 0; sp < s; ++sp)
        x = fminf(eF[sp * 64 + jl], fminf(x + (float)SEGR, LARGEf));
    float y = LARGEf;                         // bwd inflow from below
    for (int sp = SEG - 1; sp > s; --sp)
        y = fminf(eB[sp * 64 + jl], fminf(y + (float)SEGR, LARGEf));
#pragma unroll 8
    for (int i = 0; i < SEGR; ++i) {
        unsigned char uf = ldsF[tid * STRb + i];
        unsigned char ub = ldsB[tid * STRb + i];
        float lf = (uf == 255u) ? LARGEf : (float)uf;
        float lb = (ub == 255u) ? LARGEf : (float)ub;
        float f = fminf(lf, fminf(x + (float)(i + 1), LARGEf));
        float w = fminf(lb, fminf(y + (float)(SEGR - i), LARGEf));
        float g = fminf(f, w);
        gp[(r0 + i) * Wn + j] = g * g;
    }
}

// ---------------------------------------------------------------------------
// Kernel D: row pass, both polarities fused, outward scan with early exit.
// Exact (integer fp32 candidates; min order-independent). field written
// in place over g2 plane m.
// ---------------------------------------------------------------------------
__global__ void rowpass_kernel(float* __restrict__ g2,
                               const unsigned int* __restrict__ fgflags) {
    int blk = blockIdx.x;             // 0 .. NMASK*H-1
    int m = blk >> 8;                 // / Hn
    int i = blk & (Hn - 1);
    int j = threadIdx.x;
    if (!mask_has_fg(fgflags, m)) return;
    __shared__ float2 rAB[Wn];
    float* rowp = g2 + (size_t)m * HWn + i * Wn;                  // edt(mask) g2
    const float* rowq = g2 + (size_t)(m + NMASK) * HWn + i * Wn;  // edt(~mask) g2
    float a = rowp[j];
    float b = rowq[j];
    rAB[j] = make_float2(a, b);
    __syncthreads();
    float m0 = a, m1 = b;             // candidate k=0
    for (int k = 1; k < Wn; ++k) {
        float k2 = (float)(k * k);
        if (k2 >= m0 && k2 >= m1) break;
        int jl = j - k, jr = j + k;
        if (jl < 0 && jr >= Wn) break;
        if (jl >= 0) {
            float2 v = rAB[jl];
            m0 = fminf(m0, k2 + v.x);
            m1 = fminf(m1, k2 + v.y);
        }
        if (jr < Wn) {
            float2 v = rAB[jr];
            m0 = fminf(m0, k2 + v.x);
            m1 = fminf(m1, k2 + v.y);
        }
    }
    rowp[j] = sqrtf(m0) + sqrtf(m1);   // field = edt(mask) + edt(~mask)
}

// ---------------------------------------------------------------------------
// Kernel E: loss accumulation (deterministic block partials, double precision)
// ---------------------------------------------------------------------------
__global__ void loss_kernel(const float* __restrict__ pred,
                            const int* __restrict__ target,
                            const float* __restrict__ field,   // g2 planes 0..95
                            const unsigned int* __restrict__ fgflags,
                            double* __restrict__ partials) {
    int pix = blockIdx.x * blockDim.x + threadIdx.x;
    int b = pix >> 16;
    int p = pix & (HWn - 1);
    float v[Cn];
    float mx = -3.4e38f;
#pragma unroll
    for (int c = 0; c < Cn; ++c) {
        v[c] = pred[(size_t)(b * Cn + c) * HWn + p];
        mx = fmaxf(mx, v[c]);
    }
    int t = target[pix];
    float raw_t = 0.f;
    float s = 0.f;
#pragma unroll
    for (int c = 0; c < Cn; ++c) {
        if (c == t) raw_t = v[c];
        v[c] = expf(v[c] - mx);
        s += v[c];
    }
    float logp_t = raw_t - mx - logf(s);
    unsigned pfg = fgflags[b], tfg = fgflags[4 + b];
    double acc = 0.0;
#pragma unroll
    for (int c = 0; c < Cn; ++c) {
        float prob = v[c] / s;
        float oh = (c == t) ? 1.0f : 0.0f;
        float err = (prob - oh) * (prob - oh);
        int mpid = b * Cn + c;
        int mtid = Bn * Cn + b * Cn + c;
        float fp = ((pfg >> c) & 1) ? field[(size_t)mpid * HWn + p] : 0.0f;
        float ft = ((tfg >> c) & 1) ? field[(size_t)mtid * HWn + p] : 0.0f;
        float dist = fp * fp + ft * ft;   // ALPHA = 2
        acc += (double)(err * dist);
    }
    __shared__ double shl[256];
    __shared__ double shc[256];
    shl[threadIdx.x] = acc;
    shc[threadIdx.x] = (double)logp_t;
    __syncthreads();
    for (int s2 = 128; s2 > 0; s2 >>= 1) {
        if (threadIdx.x < s2) {
            shl[threadIdx.x] += shl[threadIdx.x + s2];
            shc[threadIdx.x] += shc[threadIdx.x + s2];
        }
        __syncthreads();
    }
    if (threadIdx.x == 0) {
        partials[blockIdx.x] = shl[0];
        partials[1024 + blockIdx.x] = shc[0];
    }
}

// ---------------------------------------------------------------------------
// Kernel F: final reduction -> scalar
// ---------------------------------------------------------------------------
__global__ void final_kernel(const double* __restrict__ partials,
                             float* __restrict__ out) {
    int tid = threadIdx.x;
    double a = 0.0, ce = 0.0;
    for (int i = tid; i < 1024; i += 256) {
        a  += partials[i];
        ce += partials[1024 + i];
    }
    __shared__ double sa[256], sc[256];
    sa[tid] = a; sc[tid] = ce;
    __syncthreads();
    for (int s = 128; s > 0; s >>= 1) {
        if (tid < s) { sa[tid] += sa[tid + s]; sc[tid] += sc[tid + s]; }
        __syncthreads();
    }
    if (tid == 0) {
        double loss_sum = sa[0] / (double)NPIX;        // sum_c mean_{b,h,w}
        double cem = -sc[0] / (double)NPIX;            // ce
        double res = loss_sum / (double)Cn / (double)Bn / 3.0 + cem;
        out[0] = (float)res;
    }
}

// ---------------------------------------------------------------------------
extern "C" void kernel_launch(void* const* d_in, const int* in_sizes, int n_in,
                              void* d_out, int out_size, void* d_ws, size_t ws_size,
                              hipStream_t stream) {
    const float* pred  = (const float*)d_in[0];
    const int* target  = (const int*)d_in[1];
    float* out = (float*)d_out;
    char* ws = (char*)d_ws;

    // workspace layout (~54 MB total)
    unsigned char* masks = (unsigned char*)ws;                       // 96*65536 B
    size_t off = (size_t)NMASK * HWn;
    float* g2 = (float*)(ws + off);                                  // 192*65536*4 B
    off += (size_t)NJOB * HWn * 4;
    unsigned int* fgflags = (unsigned int*)(ws + off);               // 8 u32 (pad 512)
    off += 512;
    double* partials = (double*)(ws + off);                          // 2048*8 B

    zero_kernel<<<1, 64, 0, stream>>>(fgflags);
    masks_kernel<<<NPIX / 256, 256, 0, stream>>>(pred, target, masks, fgflags);
    colpass_kernel<<<NJOB * SEG, 256, 0, stream>>>(masks, fgflags, g2);
    rowpass_kernel<<<NMASK * Hn, 256, 0, stream>>>(g2, fgflags);
    loss_kernel<<<NPIX / 256, 256, 0, stream>>>(pred, target, g2, fgflags, partials);
    final_kernel<<<1, 256, 0, stream>>>(partials, out);
}

// Round 4
// 113.194 us; speedup vs baseline: 2.4345x; 1.2386x over previous
//
#include <hip/hip_runtime.h>
#include <math.h>

// Problem constants (match reference)
constexpr int Bn = 4, Cn = 12, Hn = 256, Wn = 256;
constexpr int HWn  = Hn * Wn;        // 65536
constexpr int NPIX = Bn * HWn;       // 262144
constexpr int NMASK = 2 * Bn * Cn;   // 96 masks (48 pred + 48 target)
constexpr int NJOB  = 2 * NMASK;     // 192 EDT jobs (edt(mask), edt(~mask))
constexpr float LARGEf  = 1.0e6f;

// fgflags layout: [0..3] = predfg bitmask per batch (bit c), [4..7] = tgtfg

// ---------------------------------------------------------------------------
// Kernel Z: zero the fg flag words
// ---------------------------------------------------------------------------
__global__ void zero_kernel(unsigned int* __restrict__ fgflags) {
    if (threadIdx.x < 8) fgflags[threadIdx.x] = 0u;
}

// ---------------------------------------------------------------------------
// Kernel A: per-pixel softmax -> pred masks (prob>0.5) and target one-hot
// masks; also accumulates per-mask has_fg bits via block OR + atomicOr.
// ---------------------------------------------------------------------------
__global__ void masks_kernel(const float* __restrict__ pred,
                             const int* __restrict__ target,
                             unsigned char* __restrict__ masks,
                             unsigned int* __restrict__ fgflags) {
    int pix = blockIdx.x * blockDim.x + threadIdx.x;   // grid sized exactly NPIX
    int b = pix >> 16;            // / HW  (each block lies within one b)
    int p = pix & (HWn - 1);
    float v[Cn];
    float mx = -3.4e38f;
#pragma unroll
    for (int c = 0; c < Cn; ++c) {
        v[c] = pred[(size_t)(b * Cn + c) * HWn + p];
        mx = fmaxf(mx, v[c]);
    }
    float s = 0.f;
#pragma unroll
    for (int c = 0; c < Cn; ++c) { v[c] = expf(v[c] - mx); s += v[c]; }
    int t = target[pix];
    unsigned word = 1u << (Cn + t);   // target one-hot fg bit
#pragma unroll
    for (int c = 0; c < Cn; ++c) {
        float prob = v[c] / s;
        int pb = (prob > 0.5f) ? 1 : 0;
        word |= (unsigned)pb << c;
        masks[(size_t)(b * Cn + c) * HWn + p] = (unsigned char)pb;           // pred mask
        masks[(size_t)(Bn * Cn + b * Cn + c) * HWn + p] = (c == t) ? 1 : 0;  // target mask
    }
    __shared__ unsigned sh[256];
    sh[threadIdx.x] = word;
    __syncthreads();
    for (int s2 = 128; s2 > 0; s2 >>= 1) {
        if (threadIdx.x < s2) sh[threadIdx.x] |= sh[threadIdx.x + s2];
        __syncthreads();
    }
    if (threadIdx.x == 0) {
        unsigned w = sh[0];
        atomicOr(&fgflags[b], w & 0xFFFu);
        atomicOr(&fgflags[4 + b], w >> Cn);
    }
}

__device__ __forceinline__ int mask_has_fg(const unsigned int* fgflags, int m) {
    int mm = (m < Bn * Cn) ? m : m - Bn * Cn;
    int b = mm / Cn, c = mm % Cn;
    unsigned fg = (m < Bn * Cn) ? fgflags[b] : fgflags[4 + b];
    return (fg >> c) & 1;
}

// ---------------------------------------------------------------------------
// Kernel C: segmented column pass. Block = (job jb, column-group of 64).
// 4 segments of 64 rows per column, one thread per (segment, column).
// Local fwd/bwd scans -> LDS (u8, 255 = LARGE sentinel); combine via segment
// end-states: inflow in[s] = min(e[s-1], min(in[s-1]+64, LARGE));
// true[i] = min(loc[i], min(inflow + steps, LARGE)). Exact integer fp32.
// ---------------------------------------------------------------------------
constexpr int SEG  = 4;
constexpr int SEGR = Hn / SEG;   // 64
constexpr int STRb = 68;         // LDS byte stride per thread (17 words, coprime banks)

__global__ void colpass_kernel(const unsigned char* __restrict__ masks,
                               const unsigned int* __restrict__ fgflags,
                               float* __restrict__ g2) {
    int blk = blockIdx.x;         // 0..767
    int jb = blk >> 2;            // job 0..191
    int cg = blk & 3;             // column group
    int m  = (jb < NMASK) ? jb : jb - NMASK;
    if (!mask_has_fg(fgflags, m)) return;   // field plane never consumed
    int invert = (jb < NMASK);    // feature = !mask for edt(mask)
    int tid = threadIdx.x;
    int s  = tid >> 6;            // segment 0..3 (uniform per wave)
    int jl = tid & 63;
    int j  = cg * 64 + jl;
    int r0 = s * SEGR;
    const unsigned char* mp = masks + (size_t)m * HWn;
    float* gp = g2 + (size_t)jb * HWn;

    __shared__ unsigned char ldsF[256 * STRb];
    __shared__ unsigned char ldsB[256 * STRb];
    __shared__ float eF[256], eB[256];

    unsigned b0 = 0, b1 = 0;
    float c = LARGEf;
    for (int i = 0; i < SEGR; ++i) {
        int v = mp[(r0 + i) * Wn + j];
        int feat = invert ? (v == 0) : (v != 0);
        if (i < 32) b0 |= (unsigned)feat << i; else b1 |= (unsigned)feat << (i - 32);
        c = feat ? 0.f : fminf(c + 1.f, LARGEf);
        ldsF[tid * STRb + i] = (unsigned char)fminf(c, 255.f);   // <=63 or sentinel 255
    }
    eF[tid] = c;
    c = LARGEf;
    for (int i = SEGR - 1; i >= 0; --i) {
        int feat = (int)(((i < 32) ? (b0 >> i) : (b1 >> (i - 32))) & 1u);
        c = feat ? 0.f : fminf(c + 1.f, LARGEf);
        ldsB[tid * STRb + i] = (unsigned char)fminf(c, 255.f);
    }
    eB[tid] = c;
    __syncthreads();
    float x = LARGEf;                         // fwd inflow to my segment
    for (int sp = 0; sp < s; ++sp)
        x = fminf(eF[sp * 64 + jl], fminf(x + (float)SEGR, LARGEf));
    float y = LARGEf;                         // bwd inflow from below
    for (int sp = SEG - 1; sp > s; --sp)
        y = fminf(eB[sp * 64 + jl], fminf(y + (float)SEGR, LARGEf));
#pragma unroll 8
    for (int i = 0; i < SEGR; ++i) {
        unsigned char uf = ldsF[tid * STRb + i];
        unsigned char ub = ldsB[tid * STRb + i];
        float lf = (uf == 255u) ? LARGEf : (float)uf;
        float lb = (ub == 255u) ? LARGEf : (float)ub;
        float f = fminf(lf, fminf(x + (float)(i + 1), LARGEf));
        float w = fminf(lb, fminf(y + (float)(SEGR - i), LARGEf));
        float g = fminf(f, w);
        gp[(r0 + i) * Wn + j] = g * g;
    }
}

// ---------------------------------------------------------------------------
// Kernel D: row pass. Outward scan, SPLIT per polarity (each loop exits on
// its own convergence: iters ~ L_A + L_B instead of 2*max), with 256-elem
// LDS padding of X = fl(1e6^2) on both sides for unconditional loads.
// Padded candidates fl(X+k^2) >= X >= every real g2 value >= running min,
// so they never change the result (exact). Incremental k^2 (exact ints).
// field written in place over g2 plane m.
// ---------------------------------------------------------------------------
constexpr int RPAD = 256;

__device__ __forceinline__ float outward_min(const float* __restrict__ r,
                                             int j, float m0) {
    // r points at padded row base; real row at r[RPAD .. RPAD+Wn-1]
    const float* pl = r + RPAD + j;
    float k2 = 1.f;
    for (int k = 1; k < Wn; ++k) {
        if (k2 >= m0) break;
        m0 = fminf(m0, k2 + pl[-k]);
        m0 = fminf(m0, k2 + pl[k]);
        k2 += (float)(2 * k + 1);
    }
    return m0;
}

__global__ void rowpass_kernel(float* __restrict__ g2,
                               const unsigned int* __restrict__ fgflags) {
    int blk = blockIdx.x;             // 0 .. NMASK*H-1
    int m = blk >> 8;                 // / Hn
    int i = blk & (Hn - 1);
    int j = threadIdx.x;
    if (!mask_has_fg(fgflags, m)) return;
    const float X = LARGEf * LARGEf;  // fl(1e12)
    __shared__ float rA[Wn + 2 * RPAD];
    __shared__ float rB[Wn + 2 * RPAD];
    float* rowp = g2 + (size_t)m * HWn + i * Wn;                  // edt(mask) g2
    const float* rowq = g2 + (size_t)(m + NMASK) * HWn + i * Wn;  // edt(~mask) g2
    float a = rowp[j];
    float b = rowq[j];
    rA[j] = X; rA[RPAD + Wn + j] = X; rA[RPAD + j] = a;
    rB[j] = X; rB[RPAD + Wn + j] = X; rB[RPAD + j] = b;
    __syncthreads();
    float m0 = outward_min(rA, j, a);
    float m1 = outward_min(rB, j, b);
    rowp[j] = sqrtf(m0) + sqrtf(m1);   // field = edt(mask) + edt(~mask)
}

// ---------------------------------------------------------------------------
// Kernel E: loss accumulation (deterministic block partials, double precision)
// ---------------------------------------------------------------------------
__global__ void loss_kernel(const float* __restrict__ pred,
                            const int* __restrict__ target,
                            const float* __restrict__ field,   // g2 planes 0..95
                            const unsigned int* __restrict__ fgflags,
                            double* __restrict__ partials) {
    int pix = blockIdx.x * blockDim.x + threadIdx.x;
    int b = pix >> 16;
    int p = pix & (HWn - 1);
    float v[Cn];
    float mx = -3.4e38f;
#pragma unroll
    for (int c = 0; c < Cn; ++c) {
        v[c] = pred[(size_t)(b * Cn + c) * HWn + p];
        mx = fmaxf(mx, v[c]);
    }
    int t = target[pix];
    float raw_t = 0.f;
    float s = 0.f;
#pragma unroll
    for (int c = 0; c < Cn; ++c) {
        if (c == t) raw_t = v[c];
        v[c] = expf(v[c] - mx);
        s += v[c];
    }
    float logp_t = raw_t - mx - logf(s);
    unsigned pfg = fgflags[b], tfg = fgflags[4 + b];
    double acc = 0.0;
#pragma unroll
    for (int c = 0; c < Cn; ++c) {
        float prob = v[c] / s;
        float oh = (c == t) ? 1.0f : 0.0f;
        float err = (prob - oh) * (prob - oh);
        int mpid = b * Cn + c;
        int mtid = Bn * Cn + b * Cn + c;
        float fp = ((pfg >> c) & 1) ? field[(size_t)mpid * HWn + p] : 0.0f;
        float ft = ((tfg >> c) & 1) ? field[(size_t)mtid * HWn + p] : 0.0f;
        float dist = fp * fp + ft * ft;   // ALPHA = 2
        acc += (double)(err * dist);
    }
    __shared__ double shl[256];
    __shared__ double shc[256];
    shl[threadIdx.x] = acc;
    shc[threadIdx.x] = (double)logp_t;
    __syncthreads();
    for (int s2 = 128; s2 > 0; s2 >>= 1) {
        if (threadIdx.x < s2) {
            shl[threadIdx.x] += shl[threadIdx.x + s2];
            shc[threadIdx.x] += shc[threadIdx.x + s2];
        }
        __syncthreads();
    }
    if (threadIdx.x == 0) {
        partials[blockIdx.x] = shl[0];
        partials[1024 + blockIdx.x] = shc[0];
    }
}

// ---------------------------------------------------------------------------
// Kernel F: final reduction -> scalar
// ---------------------------------------------------------------------------
__global__ void final_kernel(const double* __restrict__ partials,
                             float* __restrict__ out) {
    int tid = threadIdx.x;
    double a = 0.0, ce = 0.0;
    for (int i = tid; i < 1024; i += 256) {
        a  += partials[i];
        ce += partials[1024 + i];
    }
    __shared__ double sa[256], sc[256];
    sa[tid] = a; sc[tid] = ce;
    __syncthreads();
    for (int s = 128; s > 0; s >>= 1) {
        if (tid < s) { sa[tid] += sa[tid + s]; sc[tid] += sc[tid + s]; }
        __syncthreads();
    }
    if (tid == 0) {
        double loss_sum = sa[0] / (double)NPIX;        // sum_c mean_{b,h,w}
        double cem = -sc[0] / (double)NPIX;            // ce
        double res = loss_sum / (double)Cn / (double)Bn / 3.0 + cem;
        out[0] = (float)res;
    }
}

// ---------------------------------------------------------------------------
extern "C" void kernel_launch(void* const* d_in, const int* in_sizes, int n_in,
                              void* d_out, int out_size, void* d_ws, size_t ws_size,
                              hipStream_t stream) {
    const float* pred  = (const float*)d_in[0];
    const int* target  = (const int*)d_in[1];
    float* out = (float*)d_out;
    char* ws = (char*)d_ws;

    // workspace layout (~54 MB total)
    unsigned char* masks = (unsigned char*)ws;                       // 96*65536 B
    size_t off = (size_t)NMASK * HWn;
    float* g2 = (float*)(ws + off);                                  // 192*65536*4 B
    off += (size_t)NJOB * HWn * 4;
    unsigned int* fgflags = (unsigned int*)(ws + off);               // 8 u32 (pad 512)
    off += 512;
    double* partials = (double*)(ws + off);                          // 2048*8 B

    zero_kernel<<<1, 64, 0, stream>>>(fgflags);
    masks_kernel<<<NPIX / 256, 256, 0, stream>>>(pred, target, masks, fgflags);
    colpass_kernel<<<NJOB * SEG, 256, 0, stream>>>(masks, fgflags, g2);
    rowpass_kernel<<<NMASK * Hn, 256, 0, stream>>>(g2, fgflags);
    loss_kernel<<<NPIX / 256, 256, 0, stream>>>(pred, target, g2, fgflags, partials);
    final_kernel<<<1, 256, 0, stream>>>(partials, out);
}